// Round 1
// baseline (1953.159 us; speedup 1.0000x reference)
//
#include <hip/hip_runtime.h>
#include <hip/hip_bf16.h>
#include <math.h>

// Problem constants (from reference)
#define N_NODES 10000
#define KNBR    16
#define EDGEF   32
#define HID     64
#define MULT    8
#define NL      2
#define DIM     4
#define OUT_MULT 24          // 3*MULT
#define NHEADS  4
#define HEAD_DIM 8
#define E_TOT   (N_NODES*KNBR)   // 160000

#define EPB 128              // edges per block (= 8 nodes)
#define TPB 128              // 2 waves; lane == edge
#define NODES_PB (EPB/KNBR)  // 8
#define LDS_STRIDE 97        // 96 floats kqv + 1 pad (96 % 32 == 0 would alias banks)

__global__ __launch_bounds__(TPB)
void esa_fused(const float* __restrict__ basis1,   // (E, DIM, NL)
               const float* __restrict__ basis2,   // (E, NL, DIM)
               const float* __restrict__ edge_feats,// (E, 32)
               const float* __restrict__ f,        // (N, MULT, DIM)
               const float* __restrict__ W1,       // (64, 32)
               const float* __restrict__ b1,       // (64)
               const float* __restrict__ W2,       // (768, 64)
               const float* __restrict__ b2,       // (768)
               const int*   __restrict__ nbr,      // (N, K) flat
               float*       __restrict__ out)      // (N, MULT, DIM)
{
    __shared__ float lds[EPB * LDS_STRIDE];

    const int tid = threadIdx.x;
    const int e   = blockIdx.x * EPB + tid;   // grid sized exactly: e < E_TOT

    // ================= Phase A: per-edge pipeline (one edge per lane) ========
    // ---- load edge feats (32 f32) into regs
    float ef[EDGEF];
    {
        const float4* p = reinterpret_cast<const float4*>(edge_feats + (size_t)e * EDGEF);
        #pragma unroll
        for (int i = 0; i < EDGEF/4; ++i) {
            float4 v = p[i];
            ef[i*4+0]=v.x; ef[i*4+1]=v.y; ef[i*4+2]=v.z; ef[i*4+3]=v.w;
        }
    }
    // ---- h = relu(W1 @ ef + b1); W1/b1 uniform -> scalar loads
    float h[HID];
    #pragma unroll
    for (int j = 0; j < HID; ++j) {
        const float* w = W1 + j*EDGEF;
        float a0=0.f, a1=0.f, a2=0.f, a3=0.f;
        #pragma unroll
        for (int i = 0; i < EDGEF; i += 4) {
            a0 += w[i+0]*ef[i+0];
            a1 += w[i+1]*ef[i+1];
            a2 += w[i+2]*ef[i+2];
            a3 += w[i+3]*ef[i+3];
        }
        float s = (a0+a1) + (a2+a3) + b1[j];
        h[j] = s > 0.f ? s : 0.f;
    }
    // ---- gather f[src] (32 f32)
    const int src = nbr[e];
    float fs[MULT*DIM];
    {
        const float4* p = reinterpret_cast<const float4*>(f + (size_t)src * (MULT*DIM));
        #pragma unroll
        for (int i = 0; i < (MULT*DIM)/4; ++i) {
            float4 v = p[i];
            fs[i*4+0]=v.x; fs[i*4+1]=v.y; fs[i*4+2]=v.z; fs[i*4+3]=v.w;
        }
    }
    // ---- basis1 (8 f32): layout [d][l]
    float bas1[DIM*NL];
    {
        const float4* p = reinterpret_cast<const float4*>(basis1 + (size_t)e * (DIM*NL));
        float4 v0 = p[0], v1 = p[1];
        bas1[0]=v0.x; bas1[1]=v0.y; bas1[2]=v0.z; bas1[3]=v0.w;
        bas1[4]=v1.x; bas1[5]=v1.y; bas1[6]=v1.z; bas1[7]=v1.w;
    }
    // ---- tmp[c = m*2+l] = sum_d fs[m,d] * bas1[d,l]
    float tp[MULT*NL];
    #pragma unroll
    for (int m = 0; m < MULT; ++m) {
        #pragma unroll
        for (int l = 0; l < NL; ++l) {
            float a = 0.f;
            #pragma unroll
            for (int d = 0; d < DIM; ++d)
                a += fs[m*DIM+d] * bas1[d*NL+l];
            tp[m*NL+l] = a;
        }
    }
    // ---- basis2 (8 f32): layout [l][d]
    float bas2[NL*DIM];
    {
        const float4* p = reinterpret_cast<const float4*>(basis2 + (size_t)e * (NL*DIM));
        float4 v0 = p[0], v1 = p[1];
        bas2[0]=v0.x; bas2[1]=v0.y; bas2[2]=v0.z; bas2[3]=v0.w;
        bas2[4]=v1.x; bas2[5]=v1.y; bas2[6]=v1.z; bas2[7]=v1.w;
    }

    // ---- main: kqv[om][d] = sum_l t2[l]*bas2[l][d];
    //      t2[l] = sum_c (W2[(om*2+l)*16+c,:]·h + b2[..]) * tp[c]
    // W2/b2 uniform-indexed -> scalar loads; h lives in VGPRs.
    float* base = lds + tid * LDS_STRIDE;
    for (int om = 0; om < OUT_MULT; ++om) {
        float t2[NL];
        #pragma unroll
        for (int l = 0; l < NL; ++l) {
            float acc = 0.f;
            #pragma unroll
            for (int c = 0; c < 16; ++c) {
                const int row = (om*NL + l)*16 + c;
                const float* w = W2 + row*HID;
                float u0=0.f,u1=0.f,u2=0.f,u3=0.f;
                #pragma unroll
                for (int k = 0; k < HID; k += 4) {
                    u0 += w[k+0]*h[k+0];
                    u1 += w[k+1]*h[k+1];
                    u2 += w[k+2]*h[k+2];
                    u3 += w[k+3]*h[k+3];
                }
                float u = (u0+u1) + (u2+u3) + b2[row];
                acc += u * tp[c];
            }
            t2[l] = acc;
        }
        #pragma unroll
        for (int d = 0; d < DIM; ++d)
            base[om*DIM + d] = t2[0]*bas2[d] + t2[1]*bas2[DIM + d];
    }

    __syncthreads();

    // ================= Phase B: attention (one node per wave-iter) ==========
    // lane = kk*4 + hh ; butterfly over kk bits (xor masks 4,8,16,32)
    const int w    = tid >> 6;    // wave id (0..1)
    const int lane = tid & 63;
    const int kk   = lane >> 2;   // neighbor 0..15
    const int hh   = lane & 3;    // head 0..3

    for (int it = 0; it < NODES_PB/2; ++it) {
        const int nl   = w*(NODES_PB/2) + it;          // 0..7
        const int node = blockIdx.x * NODES_PB + nl;
        const float* eb = lds + (nl*KNBR + kk) * LDS_STRIDE;

        float k8[HEAD_DIM], q8[HEAD_DIM], v8[HEAD_DIM];
        #pragma unroll
        for (int i = 0; i < HEAD_DIM; ++i) {
            k8[i] = eb[      hh*HEAD_DIM + i];   // om 0..7   -> flat [0,32)
            q8[i] = eb[32 +  hh*HEAD_DIM + i];   // om 8..15  -> flat [32,64)
            v8[i] = eb[64 +  hh*HEAD_DIM + i];   // om 16..23 -> flat [64,96)
        }
        // q_node = mean over k (sum via butterfly, fold /16 into scale)
        float qn[HEAD_DIM];
        #pragma unroll
        for (int i = 0; i < HEAD_DIM; ++i) qn[i] = q8[i];
        #pragma unroll
        for (int m = 4; m <= 32; m <<= 1) {
            #pragma unroll
            for (int i = 0; i < HEAD_DIM; ++i)
                qn[i] += __shfl_xor(qn[i], m);
        }
        float s = 0.f;
        #pragma unroll
        for (int i = 0; i < HEAD_DIM; ++i) s += qn[i]*k8[i];
        s *= 0.0220970869120796f;   // (1/16) * 8^-0.5

        // softmax over the 16 kk-lanes
        float mx = s;
        #pragma unroll
        for (int m = 4; m <= 32; m <<= 1) mx = fmaxf(mx, __shfl_xor(mx, m));
        float ex = __expf(s - mx);
        float den = ex;
        #pragma unroll
        for (int m = 4; m <= 32; m <<= 1) den += __shfl_xor(den, m);
        float wgt = ex / den;

        float o[HEAD_DIM];
        #pragma unroll
        for (int i = 0; i < HEAD_DIM; ++i) o[i] = wgt * v8[i];
        #pragma unroll
        for (int m = 4; m <= 32; m <<= 1) {
            #pragma unroll
            for (int i = 0; i < HEAD_DIM; ++i)
                o[i] += __shfl_xor(o[i], m);
        }
        if (kk == 0) {
            float4 o0 = make_float4(o[0],o[1],o[2],o[3]);
            float4 o1 = make_float4(o[4],o[5],o[6],o[7]);
            float4* dst = reinterpret_cast<float4*>(out + (size_t)node*(MULT*DIM) + hh*HEAD_DIM);
            dst[0] = o0; dst[1] = o1;
        }
    }
}

extern "C" void kernel_launch(void* const* d_in, const int* in_sizes, int n_in,
                              void* d_out, int out_size, void* d_ws, size_t ws_size,
                              hipStream_t stream) {
    const float* basis1     = (const float*)d_in[0];
    const float* basis2     = (const float*)d_in[1];
    const float* edge_feats = (const float*)d_in[2];
    const float* f          = (const float*)d_in[3];
    const float* W1         = (const float*)d_in[4];
    const float* b1         = (const float*)d_in[5];
    const float* W2         = (const float*)d_in[6];
    const float* b2         = (const float*)d_in[7];
    const int*   nbr        = (const int*)d_in[8];
    float* out = (float*)d_out;

    esa_fused<<<E_TOT/EPB, TPB, 0, stream>>>(basis1, basis2, edge_feats, f,
                                             W1, b1, W2, b2, nbr, out);
}

// Round 5
// 117.655 us; speedup vs baseline: 16.6008x; 16.6008x over previous
//
#include <hip/hip_runtime.h>
#include <hip/hip_bf16.h>
#include <math.h>

#define N_NODES 10000
#define KNBR    16
#define EDGEF   32
#define HID     64
#define MULT    8
#define NL      2
#define DIM     4
#define OUT_MULT 24
#define NHEADS  4
#define HEAD_DIM 8
#define E_TOT   (N_NODES*KNBR)

#define EPB 128
#define TPB 256
#define NODES_PB 8
#define NSLICE 33            // K' = 1056 = 33 slices of 32 (last slice carries b2, zero-padded)

typedef float    f32x4 __attribute__((ext_vector_type(4)));
typedef _Float16 f16x8 __attribute__((ext_vector_type(8)));

// ws layout (halves): Bf1[4][64][8] | Bf2[3][33][64][8]
#define BF1_HALVES (4*64*8)
#define BF2_HALVES (3*NSLICE*64*8)
#define WS_HALVES  (BF1_HALVES + BF2_HALVES)

// ---------------- prep: fragment-ready fp16 weights into d_ws ----------------
__global__ __launch_bounds__(256)
void esa_prep(const float* __restrict__ W1, const float* __restrict__ W2,
              const float* __restrict__ b2, _Float16* __restrict__ wsh)
{
    int i = blockIdx.x * 256 + threadIdx.x;
    if (i >= WS_HALVES) return;
    float v;
    if (i < BF1_HALVES) {
        int j = i & 7, lane = (i >> 3) & 63, t = i >> 9;
        int k = ((lane >> 4) << 3) + j;          // 0..31
        int n = (t << 4) + (lane & 15);          // 0..63
        v = W1[n * EDGEF + k];
    } else {
        int i2 = i - BF1_HALVES;
        int j = i2 & 7, lane = (i2 >> 3) & 63;
        int st = i2 >> 9;                        // t*33 + s
        int s = st % NSLICE, t = st / NSLICE;
        int k = (s << 5) + ((lane >> 4) << 3) + j;   // 0..1055
        int n = (t << 4) + (lane & 15);              // oml 0..47
        if (k < 1024)      v = W2[(n * 16 + (k >> 6)) * HID + (k & 63)];
        else if (k < 1040) v = b2[n * 16 + (k - 1024)];
        else               v = 0.f;
    }
    wsh[i] = (_Float16)v;
}

// ---------------- fused main kernel ----------------
// LDS: t2 [128][52] f32 @0 (26624) | h [128][72] f16 @26624 (18432)
//      tp [128][16] f16 @45056 (4096) | bas2 [128][8] f32 @49152 (4096) = 53248 B
__global__ __launch_bounds__(TPB)
void esa_main(const float* __restrict__ basis1, const float* __restrict__ basis2,
              const float* __restrict__ edge_feats, const float* __restrict__ f,
              const float* __restrict__ b1, const int* __restrict__ nbr,
              const _Float16* __restrict__ wsh, float* __restrict__ out)
{
    __shared__ __align__(16) unsigned char smem[53248];
    float*    t2  = (float*)smem;                       // stride 52 f32 (208 B, 16B-aligned)
    _Float16* hls = (_Float16*)(smem + 26624);          // stride 72 f16 (144 B, 16B-aligned)
    _Float16* tpl = (_Float16*)(smem + 45056);          // stride 16 f16 (32 B)
    float*    b2l = (float*)(smem + 49152);             // stride 8 f32 (32 B)

    const int tid  = threadIdx.x;
    const int eb   = blockIdx.x * EPB;
    const int lane = tid & 63;
    const int w    = tid >> 6;
    const int lo   = lane & 15, hi = lane >> 4;

    // ===== phase 0: tp (tensor-product coeffs) + bas2 stage =====
    {
        int el = tid >> 1, hf = tid & 1;
        int e  = eb + el;
        int src = nbr[e];
        const float4* b1p = (const float4*)(basis1 + (size_t)e * 8);
        float4 u0 = b1p[0], u1 = b1p[1];                 // [d][l] layout
        float bl0[4] = {u0.x, u0.z, u1.x, u1.z};         // l=0, d=0..3
        float bl1[4] = {u0.y, u0.w, u1.y, u1.w};         // l=1
        const float4* fp = (const float4*)(f + (size_t)src * 32 + hf * 16);
        _Float16 tpv[8];
        #pragma unroll
        for (int mm = 0; mm < 4; ++mm) {
            float4 fv = fp[mm];
            float a0 = fv.x*bl0[0] + fv.y*bl0[1] + fv.z*bl0[2] + fv.w*bl0[3];
            float a1 = fv.x*bl1[0] + fv.y*bl1[1] + fv.z*bl1[2] + fv.w*bl1[3];
            tpv[mm*2+0] = (_Float16)a0;
            tpv[mm*2+1] = (_Float16)a1;
        }
        *(f16x8*)(tpl + el*16 + hf*8) = *(f16x8*)tpv;
        float4 b2v = ((const float4*)(basis2 + (size_t)e * 8))[hf];
        *((float4*)(b2l + el*8) + hf) = b2v;
    }

    // ===== phase 0b: MLP1 via MFMA  h = relu(ef @ W1^T + b1) =====
    {
        float b1v[4];
        #pragma unroll
        for (int t = 0; t < 4; ++t) b1v[t] = b1[t*16 + lo];
        f16x8 afr[2];
        #pragma unroll
        for (int mt = 0; mt < 2; ++mt) {
            size_t eg = (size_t)(eb + w*32 + mt*16 + lo);
            const float4* p = (const float4*)(edge_feats + eg*32 + hi*8);
            float4 x0 = p[0], x1 = p[1];
            f16x8 a;
            a[0]=(_Float16)x0.x; a[1]=(_Float16)x0.y; a[2]=(_Float16)x0.z; a[3]=(_Float16)x0.w;
            a[4]=(_Float16)x1.x; a[5]=(_Float16)x1.y; a[6]=(_Float16)x1.z; a[7]=(_Float16)x1.w;
            afr[mt] = a;
        }
        #pragma unroll
        for (int t = 0; t < 4; ++t) {
            f16x8 bfr = *(const f16x8*)(wsh + ((size_t)(t*64 + lane)) * 8);
            #pragma unroll
            for (int mt = 0; mt < 2; ++mt) {
                f32x4 acc = {0.f, 0.f, 0.f, 0.f};
                acc = __builtin_amdgcn_mfma_f32_16x16x32_f16(afr[mt], bfr, acc, 0, 0, 0);
                #pragma unroll
                for (int r = 0; r < 4; ++r) {
                    float hv = acc[r] + b1v[t];
                    hv = hv > 0.f ? hv : 0.f;
                    int el = w*32 + mt*16 + hi*4 + r;
                    hls[el*72 + t*16 + lo] = (_Float16)hv;
                }
            }
        }
    }
    __syncthreads();

    // ===== phase 1: main GEMM  t2[e,oml] = sum_k' A'[e,k'] B'[k',oml] =====
    {
        f32x4 acc[2][3];
        #pragma unroll
        for (int mt = 0; mt < 2; ++mt)
            #pragma unroll
            for (int t = 0; t < 3; ++t)
                acc[mt][t] = (f32x4){0.f, 0.f, 0.f, 0.f};

        const _Float16* Bf2 = wsh + BF1_HALVES;
        const int e0 = w*32 + lo;
        const int e1 = e0 + 16;
        const _Float16* hp0 = hls + e0*72 + hi*8;
        const _Float16* hp1 = hls + e1*72 + hi*8;
        // preload tp rows (also reused as the bias-slice A-frags)
        f16x8 tp0a = *(const f16x8*)(tpl + e0*16);
        f16x8 tp0b = *(const f16x8*)(tpl + e0*16 + 8);
        f16x8 tp1a = *(const f16x8*)(tpl + e1*16);
        f16x8 tp1b = *(const f16x8*)(tpl + e1*16 + 8);

        #pragma unroll
        for (int sp = 0; sp < 16; ++sp) {
            _Float16 t0 = (sp < 8) ? tp0a[sp & 7] : tp0b[sp & 7];
            _Float16 t1 = (sp < 8) ? tp1a[sp & 7] : tp1b[sp & 7];
            f16x8 ts0 = {t0,t0,t0,t0,t0,t0,t0,t0};
            f16x8 ts1 = {t1,t1,t1,t1,t1,t1,t1,t1};
            #pragma unroll
            for (int sh = 0; sh < 2; ++sh) {
                const int s = sp*2 + sh;
                f16x8 bfr[3];
                #pragma unroll
                for (int t = 0; t < 3; ++t)
                    bfr[t] = *(const f16x8*)(Bf2 + ((size_t)((t*NSLICE + s)*64 + lane)) * 8);
                f16x8 h0 = *(const f16x8*)(hp0 + sh*32);
                f16x8 h1 = *(const f16x8*)(hp1 + sh*32);
                f16x8 a0 = h0 * ts0;
                f16x8 a1 = h1 * ts1;
                #pragma unroll
                for (int t = 0; t < 3; ++t) {
                    acc[0][t] = __builtin_amdgcn_mfma_f32_16x16x32_f16(a0, bfr[t], acc[0][t], 0, 0, 0);
                    acc[1][t] = __builtin_amdgcn_mfma_f32_16x16x32_f16(a1, bfr[t], acc[1][t], 0, 0, 0);
                }
            }
        }
        // bias slice s=32: A' = tp (hi<2), B' = b2 frags
        {
            f16x8 z = {(_Float16)0,(_Float16)0,(_Float16)0,(_Float16)0,
                       (_Float16)0,(_Float16)0,(_Float16)0,(_Float16)0};
            f16x8 a0 = (hi == 0) ? tp0a : (hi == 1) ? tp0b : z;
            f16x8 a1 = (hi == 0) ? tp1a : (hi == 1) ? tp1b : z;
            #pragma unroll
            for (int t = 0; t < 3; ++t) {
                f16x8 bfr = *(const f16x8*)(Bf2 + ((size_t)((t*NSLICE + 32)*64 + lane)) * 8);
                acc[0][t] = __builtin_amdgcn_mfma_f32_16x16x32_f16(a0, bfr, acc[0][t], 0, 0, 0);
                acc[1][t] = __builtin_amdgcn_mfma_f32_16x16x32_f16(a1, bfr, acc[1][t], 0, 0, 0);
            }
        }
        // write t2
        #pragma unroll
        for (int mt = 0; mt < 2; ++mt)
            #pragma unroll
            for (int t = 0; t < 3; ++t)
                #pragma unroll
                for (int r = 0; r < 4; ++r)
                    t2[(w*32 + mt*16 + hi*4 + r)*52 + t*16 + lo] = acc[mt][t][r];
    }
    __syncthreads();

    // ===== phase 2: attention (wave w handles nodes it*4+w) =====
    // t2 columns are oml = om*2+l: k_ -> oml [0,16), q_ -> [16,32), v_ -> [32,48)
    const int kk = lane >> 2, hh = lane & 3;
    #pragma unroll
    for (int it = 0; it < 2; ++it) {
        int nl = it*4 + w;
        int node = blockIdx.x * NODES_PB + nl;
        int el = nl*16 + kk;
        const float* trow = t2 + el*52;
        float4 tk = *(const float4*)(trow + hh*4);
        float4 tq = *(const float4*)(trow + 16 + hh*4);
        float4 tv = *(const float4*)(trow + 32 + hh*4);
        float4 bl0 = *(const float4*)(b2l + el*8);
        float4 bl1 = *(const float4*)(b2l + el*8 + 4);
        float k8[8], q8[8], v8[8];
        const float* B0 = (const float*)&bl0;
        const float* B1 = (const float*)&bl1;
        #pragma unroll
        for (int d = 0; d < 4; ++d) {
            k8[d]   = tk.x*B0[d] + tk.y*B1[d];
            k8[4+d] = tk.z*B0[d] + tk.w*B1[d];
            q8[d]   = tq.x*B0[d] + tq.y*B1[d];
            q8[4+d] = tq.z*B0[d] + tq.w*B1[d];
            v8[d]   = tv.x*B0[d] + tv.y*B1[d];
            v8[4+d] = tv.z*B0[d] + tv.w*B1[d];
        }
        float qn[8];
        #pragma unroll
        for (int i = 0; i < 8; ++i) qn[i] = q8[i];
        #pragma unroll
        for (int m = 4; m <= 32; m <<= 1)
            #pragma unroll
            for (int i = 0; i < 8; ++i) qn[i] += __shfl_xor(qn[i], m);
        float s = 0.f;
        #pragma unroll
        for (int i = 0; i < 8; ++i) s += qn[i]*k8[i];
        s *= 0.0220970869120796f;   // (1/16) * 8^-0.5

        float mx = s;
        #pragma unroll
        for (int m = 4; m <= 32; m <<= 1) mx = fmaxf(mx, __shfl_xor(mx, m));
        float ex = __expf(s - mx);
        float den = ex;
        #pragma unroll
        for (int m = 4; m <= 32; m <<= 1) den += __shfl_xor(den, m);
        float wgt = ex / den;

        float o[8];
        #pragma unroll
        for (int i = 0; i < 8; ++i) o[i] = wgt * v8[i];
        #pragma unroll
        for (int m = 4; m <= 32; m <<= 1)
            #pragma unroll
            for (int i = 0; i < 8; ++i) o[i] += __shfl_xor(o[i], m);
        if (kk == 0) {
            float4* dst = (float4*)(out + (size_t)node*32 + hh*8);
            dst[0] = make_float4(o[0], o[1], o[2], o[3]);
            dst[1] = make_float4(o[4], o[5], o[6], o[7]);
        }
    }
}

extern "C" void kernel_launch(void* const* d_in, const int* in_sizes, int n_in,
                              void* d_out, int out_size, void* d_ws, size_t ws_size,
                              hipStream_t stream) {
    const float* basis1     = (const float*)d_in[0];
    const float* basis2     = (const float*)d_in[1];
    const float* edge_feats = (const float*)d_in[2];
    const float* f          = (const float*)d_in[3];
    const float* W1         = (const float*)d_in[4];
    const float* b1         = (const float*)d_in[5];
    const float* W2         = (const float*)d_in[6];
    const float* b2         = (const float*)d_in[7];
    const int*   nbr        = (const int*)d_in[8];
    float* out = (float*)d_out;
    _Float16* wsh = (_Float16*)d_ws;

    esa_prep<<<(WS_HALVES + 255)/256, 256, 0, stream>>>(W1, W2, b2, wsh);
    esa_main<<<E_TOT/EPB, TPB, 0, stream>>>(basis1, basis2, edge_feats, f,
                                            b1, nbr, wsh, out);
}